// Round 10
// baseline (383.272 us; speedup 1.0000x reference)
//
#include <hip/hip_runtime.h>
#include <hip/hip_bf16.h>

#define D_IN 128
#define D_OUT 64
#define BN_EPS 1e-5f
#define NB_PART 512

typedef short short8 __attribute__((ext_vector_type(8)));
typedef float f32x4 __attribute__((ext_vector_type(4)));
typedef float f32x2 __attribute__((ext_vector_type(2)));
typedef unsigned int u32x4 __attribute__((ext_vector_type(4)));
typedef unsigned int u32x2 __attribute__((ext_vector_type(2)));
typedef unsigned short ushort_t;
typedef unsigned int uint_t;

__device__ __forceinline__ float bf16lo(uint_t v) { return __uint_as_float(v << 16); }
__device__ __forceinline__ float bf16hi(uint_t v) { return __uint_as_float(v & 0xffff0000u); }
__device__ __forceinline__ float bf2f(ushort_t u) { return __uint_as_float(((uint_t)u) << 16); }
__device__ __forceinline__ ushort_t f2bf(float f) {
    union { __hip_bfloat16 h; ushort_t u; } cv;
    cv.h = __float2bfloat16(f);
    return cv.u;
}
__device__ __forceinline__ f32x4 ntload4(const float* p) {
    return __builtin_nontemporal_load((const f32x4*)p);
}

// ---------------- CSR construction ----------------

__global__ void hist_kernel(const int* __restrict__ dst, int* __restrict__ cnt, int E) {
    int i = blockIdx.x * 256 + threadIdx.x;
    if (i < E) atomicAdd(&cnt[__builtin_nontemporal_load(&dst[i])], 1);
}

// single-block exclusive scan of cnt[0..n) -> offs[0..n] and cursor[0..n)
__global__ __launch_bounds__(1024) void scan_kernel(const int* __restrict__ cnt,
                                                    int* __restrict__ offs,
                                                    int* __restrict__ cursor, int n) {
    __shared__ int wsum[16];
    __shared__ int carry_s;
    int tid = threadIdx.x;
    int lane = tid & 63, wid = tid >> 6;
    if (tid == 0) carry_s = 0;
    __syncthreads();
    const int CH = 4096; // 1024 threads * 4 elems
    for (int base = 0; base < n; base += CH) {
        int i0 = base + tid * 4;
        int v[4];
#pragma unroll
        for (int j = 0; j < 4; j++) { int i = i0 + j; v[j] = (i < n) ? cnt[i] : 0; }
        int tsum = v[0] + v[1] + v[2] + v[3];
        int sc = tsum;
#pragma unroll
        for (int off = 1; off < 64; off <<= 1) {
            int t = __shfl_up(sc, off);
            if (lane >= off) sc += t;
        }
        if (lane == 63) wsum[wid] = sc;
        __syncthreads();
        int wbase = 0;
        for (int w = 0; w < 16; w++) if (w < wid) wbase += wsum[w];
        int carry = carry_s;
        __syncthreads();
        int run = carry + wbase + sc - tsum; // exclusive prefix for first elem
#pragma unroll
        for (int j = 0; j < 4; j++) {
            int i = i0 + j;
            if (i < n) {
                offs[i] = run;
                cursor[i] = run;
            }
            run += v[j];
        }
        if (tid == 1023) carry_s = carry + wbase + sc;
        __syncthreads();
    }
    if (tid == 0) offs[n] = carry_s;
}

__global__ void scatter_kernel(const int* __restrict__ src, const int* __restrict__ dst,
                               int* __restrict__ cursor, ushort_t* __restrict__ sorted_src,
                               int E, int passW) {
    int lo = blockIdx.y * passW, hi = lo + passW;
    int i = blockIdx.x * 256 + threadIdx.x;
    if (i < E) {
        int d = __builtin_nontemporal_load(&dst[i]);
        if (d >= lo && d < hi) {
            int s = __builtin_nontemporal_load(&src[i]);
            int p = atomicAdd(&cursor[d], 1);
            sorted_src[p] = (ushort_t)s;
        }
    }
}

// ---------------- weight swizzle (all 3 layers) + cnt zeroing ----------------
// chunk (nf, kk): 64 lanes x 8 bf16; lane l elem j = W[kk*32 + (l>>4)*8 + j][nf*16 + (l&15)]

__global__ void wswz_kernel(const float* __restrict__ Wl0, const float* __restrict__ Wr0,
                            const float* __restrict__ Wl1, const float* __restrict__ Wr1,
                            const float* __restrict__ Wl2, const float* __restrict__ Wr2,
                            short* __restrict__ o0l, short* __restrict__ o0r,
                            short* __restrict__ o1l, short* __restrict__ o1r,
                            short* __restrict__ o2l, short* __restrict__ o2r,
                            int* __restrict__ cnt, int N) {
    // zero the histogram buffer (grid-stride over all 48 blocks)
    int fb = blockIdx.x + 8 * (blockIdx.y + 2 * blockIdx.z);
    for (int i = fb * 256 + threadIdx.x; i < N; i += 48 * 256) cnt[i] = 0;

    int layer = blockIdx.z;
    int Nn = (layer == 2) ? 64 : 128;
    const float* W;
    short* out;
    if (layer == 0) { W = blockIdx.y ? Wr0 : Wl0; out = blockIdx.y ? o0r : o0l; }
    else if (layer == 1) { W = blockIdx.y ? Wr1 : Wl1; out = blockIdx.y ? o1r : o1l; }
    else { W = blockIdx.y ? Wr2 : Wl2; out = blockIdx.y ? o2r : o2l; }
    int g = blockIdx.x * 256 + threadIdx.x;
    int nchunks = (Nn / 16) * 4;
    int chunk = g >> 6, lane = g & 63;
    if (chunk >= nchunks) return;
    int nf = chunk >> 2, kk = chunk & 3;
    short8 s;
#pragma unroll
    for (int j = 0; j < 8; j++) {
        float v = W[(size_t)(kk * 32 + (lane >> 4) * 8 + j) * Nn + nf * 16 + (lane & 15)];
        s[j] = (short)f2bf(v);
    }
    *(short8*)&out[((size_t)(chunk << 6) + lane) * 8] = s;
}

// ---------------- fused dual MFMA GEMM + on-the-fly BN/ReLU on A ----------------
// BF16IN=false: A is f32 (layer 0, no BN). BF16IN=true: A is bf16 + BN+ReLU fused.
// Both outputs bf16: Yb = a@Wl, Zb = a@Wr.

template <int TN, bool BF16IN>
__global__ __launch_bounds__(TN == 128 ? 256 : 128)
void gemm2_mfma(const void* __restrict__ Ain, const short* __restrict__ WlF,
                const short* __restrict__ WrF, ushort_t* __restrict__ Yb,
                ushort_t* __restrict__ Zb, const float* __restrict__ stats,
                const float* __restrict__ gamma, const float* __restrict__ beta, int M) {
    __shared__ short As[64 * 136];
    __shared__ float sc[128], sh[128];
    const int tid = threadIdx.x;
    const int lane = tid & 63;
    const int w = tid >> 6;
    const int row0 = blockIdx.x * 64;
    const int NT = (TN == 128) ? 256 : 128;

    if (BF16IN) {
        if (tid < 128) {
            float invM = 1.0f / (float)M;
            float mu = stats[tid] * invM;
            float var = stats[128 + tid] * invM - mu * mu;
            float scale = gamma[tid] * rsqrtf(var + BN_EPS);
            sc[tid] = scale;
            sh[tid] = beta[tid] - mu * scale;
        }
        __syncthreads();
    }

    for (int c = tid; c < 1024; c += NT) {
        int r = c >> 4, off = (c & 15) * 8;
        short8 v8 = {0, 0, 0, 0, 0, 0, 0, 0};
        if (row0 + r < M) {
            if (BF16IN) {
                const ushort_t* ap = (const ushort_t*)Ain + (size_t)(row0 + r) * 128 + off;
                short8 h = *(const short8*)ap;
#pragma unroll
                for (int j = 0; j < 8; j++) {
                    float f = bf2f((ushort_t)h[j]);
                    f = fmaxf(f * sc[off + j] + sh[off + j], 0.f);
                    v8[j] = (short)f2bf(f);
                }
            } else {
                const float* ap = (const float*)Ain + (size_t)(row0 + r) * 128 + off;
                f32x4 f0 = ntload4(ap);
                f32x4 f1 = ntload4(ap + 4);
#pragma unroll
                for (int j = 0; j < 4; j++) {
                    v8[j] = (short)f2bf(f0[j]);
                    v8[4 + j] = (short)f2bf(f1[j]);
                }
            }
        }
        *(short8*)&As[r * 136 + off] = v8;
    }
    __syncthreads();

    const short* WF;
    ushort_t* D;
    int col0;
    if (TN == 128) {
        bool isY = (w < 2);
        WF = isY ? WlF : WrF;
        D = isY ? Yb : Zb;
        col0 = (w & 1) * 64;
    } else {
        bool isY = (w == 0);
        WF = isY ? WlF : WrF;
        D = isY ? Yb : Zb;
        col0 = 0;
    }

    short8 a[4][4];
#pragma unroll
    for (int m = 0; m < 4; m++)
#pragma unroll
        for (int kk = 0; kk < 4; kk++)
            a[m][kk] = *(const short8*)&As[(m * 16 + (lane & 15)) * 136 + kk * 32 + (lane >> 4) * 8];

    f32x4 acc[4][4];
#pragma unroll
    for (int m = 0; m < 4; m++)
#pragma unroll
        for (int n = 0; n < 4; n++) acc[m][n] = (f32x4){0.f, 0.f, 0.f, 0.f};

#pragma unroll
    for (int kk = 0; kk < 4; kk++) {
#pragma unroll
        for (int n = 0; n < 4; n++) {
            short8 b = *(const short8*)&WF[(size_t)(((col0 >> 4) + n) * 4 + kk) * 512 + lane * 8];
#pragma unroll
            for (int m = 0; m < 4; m++)
                acc[m][n] = __builtin_amdgcn_mfma_f32_16x16x32_bf16(a[m][kk], b, acc[m][n], 0, 0, 0);
        }
    }

    // C/D: col = lane&15, row = (lane>>4)*4 + reg
#pragma unroll
    for (int m = 0; m < 4; m++) {
#pragma unroll
        for (int i = 0; i < 4; i++) {
            int gr = row0 + m * 16 + (lane >> 4) * 4 + i;
            if (gr < M) {
#pragma unroll
                for (int n = 0; n < 4; n++)
                    D[(size_t)gr * TN + col0 + n * 16 + (lane & 15)] = f2bf(acc[m][n][i]);
            }
        }
    }
}

// ---------------- aggregation (layers 0/1): Hb[node] = Zb[node] + mean(Yb[srcs]) + bias ----
// one wave = TWO nodes (one per 32-lane half, u32x2 = 4 cols/lane); 16 gathers in flight

__global__ __launch_bounds__(256) void agg128_kernel(const ushort_t* __restrict__ Yb,
                                                     const int* __restrict__ offs,
                                                     const ushort_t* __restrict__ sorted_src,
                                                     const float* __restrict__ bias,
                                                     const ushort_t* __restrict__ Zb,
                                                     ushort_t* __restrict__ Hb, int N) {
    int wv = blockIdx.x * 4 + (threadIdx.x >> 6);
    int lane = threadIdx.x & 63;
    int half = lane >> 5, l = lane & 31;
    int node = wv * 2 + half;
    if (node >= N) return;
    int s0 = offs[node], s1 = offs[node + 1];
    float a0 = 0.f, a1 = 0.f, a2 = 0.f, a3 = 0.f;
    int k = s0;
    for (; k + 16 <= s1; k += 16) {
        int idx[16];
#pragma unroll
        for (int j = 0; j < 16; j++) idx[j] = __builtin_nontemporal_load(&sorted_src[k + j]);
        u32x2 v[16];
#pragma unroll
        for (int j = 0; j < 16; j++) v[j] = *(const u32x2*)&Yb[(size_t)idx[j] * 128 + l * 4];
#pragma unroll
        for (int j = 0; j < 16; j++) {
            a0 += bf16lo(v[j][0]);
            a1 += bf16hi(v[j][0]);
            a2 += bf16lo(v[j][1]);
            a3 += bf16hi(v[j][1]);
        }
    }
    for (; k + 4 <= s1; k += 4) {
        int idx[4];
#pragma unroll
        for (int j = 0; j < 4; j++) idx[j] = __builtin_nontemporal_load(&sorted_src[k + j]);
#pragma unroll
        for (int j = 0; j < 4; j++) {
            u32x2 v = *(const u32x2*)&Yb[(size_t)idx[j] * 128 + l * 4];
            a0 += bf16lo(v[0]);
            a1 += bf16hi(v[0]);
            a2 += bf16lo(v[1]);
            a3 += bf16hi(v[1]);
        }
    }
    for (; k < s1; k++) {
        u32x2 v = *(const u32x2*)&Yb[(size_t)sorted_src[k] * 128 + l * 4];
        a0 += bf16lo(v[0]);
        a1 += bf16hi(v[0]);
        a2 += bf16lo(v[1]);
        a3 += bf16hi(v[1]);
    }
    float inv = 1.0f / fmaxf((float)(s1 - s0), 1.0f);
    float4 bb = *(const float4*)&bias[l * 4];
    u32x2 z = __builtin_nontemporal_load((const u32x2*)&Zb[(size_t)node * 128 + l * 4]);
    float h0 = bf16lo(z[0]) + a0 * inv + bb.x;
    float h1 = bf16hi(z[0]) + a1 * inv + bb.y;
    float h2 = bf16lo(z[1]) + a2 * inv + bb.z;
    float h3 = bf16hi(z[1]) + a3 * inv + bb.w;
    u32x2 o;
    o[0] = (uint_t)f2bf(h0) | ((uint_t)f2bf(h1) << 16);
    o[1] = (uint_t)f2bf(h2) | ((uint_t)f2bf(h3) << 16);
    __builtin_nontemporal_store(o, (u32x2*)&Hb[(size_t)node * 128 + l * 4]);
}

// ---------------- layer 2: agg + bias + log_softmax fused ----------------
// one wave = TWO nodes (one per 32-lane half); 8-deep gather unroll

__global__ __launch_bounds__(256) void agg_lsm_kernel(const ushort_t* __restrict__ Yb,
                                                      const int* __restrict__ offs,
                                                      const ushort_t* __restrict__ sorted_src,
                                                      const float* __restrict__ bias,
                                                      const ushort_t* __restrict__ Zb,
                                                      float* __restrict__ out, int N) {
    int wv = blockIdx.x * 4 + (threadIdx.x >> 6);
    int lane = threadIdx.x & 63;
    int half = lane >> 5, l = lane & 31;
    int node = wv * 2 + half;
    if (node >= N) return;
    int s0 = offs[node], s1 = offs[node + 1];
    float a0 = 0.f, a1 = 0.f;
    int k = s0;
    for (; k + 8 <= s1; k += 8) {
        int idx[8];
#pragma unroll
        for (int j = 0; j < 8; j++) idx[j] = __builtin_nontemporal_load(&sorted_src[k + j]);
        uint_t v[8];
#pragma unroll
        for (int j = 0; j < 8; j++) v[j] = *(const uint_t*)&Yb[(size_t)idx[j] * 64 + l * 2];
#pragma unroll
        for (int j = 0; j < 8; j++) {
            a0 += bf16lo(v[j]);
            a1 += bf16hi(v[j]);
        }
    }
    for (; k + 4 <= s1; k += 4) {
        int idx[4];
#pragma unroll
        for (int j = 0; j < 4; j++) idx[j] = __builtin_nontemporal_load(&sorted_src[k + j]);
#pragma unroll
        for (int j = 0; j < 4; j++) {
            uint_t v = *(const uint_t*)&Yb[(size_t)idx[j] * 64 + l * 2];
            a0 += bf16lo(v);
            a1 += bf16hi(v);
        }
    }
    for (; k < s1; k++) {
        uint_t v = *(const uint_t*)&Yb[(size_t)sorted_src[k] * 64 + l * 2];
        a0 += bf16lo(v);
        a1 += bf16hi(v);
    }
    float inv = 1.0f / fmaxf((float)(s1 - s0), 1.0f);
    uint_t z = *(const uint_t*)&Zb[(size_t)node * 64 + l * 2];
    float2 bb = *(const float2*)&bias[l * 2];
    float v0 = bf16lo(z) + a0 * inv + bb.x;
    float v1 = bf16hi(z) + a1 * inv + bb.y;
    float m = fmaxf(v0, v1);
#pragma unroll
    for (int off = 16; off; off >>= 1) m = fmaxf(m, __shfl_xor(m, off));
    float s = expf(v0 - m) + expf(v1 - m);
#pragma unroll
    for (int off = 16; off; off >>= 1) s += __shfl_xor(s, off);
    float ls = logf(s);
    f32x2 o;
    o[0] = v0 - m - ls;
    o[1] = v1 - m - ls;
    __builtin_nontemporal_store(o, (f32x2*)&out[(size_t)node * 64 + l * 2]);
}

// ---------------- BatchNorm stats: two-stage column reduction (bf16 input) ----------------

__global__ __launch_bounds__(256) void bn_part_kernel(const ushort_t* __restrict__ Hb,
                                                      float* __restrict__ P, int M) {
    int b = blockIdx.x;
    int R = (M + NB_PART - 1) / NB_PART;
    int r0 = b * R, r1 = min(r0 + R, M);
    int colg = (threadIdx.x & 15) * 8;
    int rowoff = threadIdx.x >> 4;
    float s[8], s2[8];
#pragma unroll
    for (int j = 0; j < 8; j++) { s[j] = 0.f; s2[j] = 0.f; }
    for (int r = r0 + rowoff; r < r1; r += 16) {
        u32x4 v = __builtin_nontemporal_load((const u32x4*)&Hb[(size_t)r * 128 + colg]);
#pragma unroll
        for (int q = 0; q < 4; q++) {
            float flo = bf16lo(v[q]);
            float fhi = bf16hi(v[q]);
            s[2 * q] += flo;
            s2[2 * q] += flo * flo;
            s[2 * q + 1] += fhi;
            s2[2 * q + 1] += fhi * fhi;
        }
    }
    __shared__ float ls[256][16];
#pragma unroll
    for (int j = 0; j < 8; j++) {
        ls[threadIdx.x][j] = s[j];
        ls[threadIdx.x][8 + j] = s2[j];
    }
    __syncthreads();
    if (threadIdx.x < 128) {
        int g = threadIdx.x >> 3, j = threadIdx.x & 7;
        float a = 0.f, c = 0.f;
#pragma unroll
        for (int kk = 0; kk < 16; kk++) {
            int id = kk * 16 + g;
            a += ls[id][j];
            c += ls[id][8 + j];
        }
        P[(size_t)b * 256 + threadIdx.x] = a;
        P[(size_t)b * 256 + 128 + threadIdx.x] = c;
    }
}

__global__ __launch_bounds__(1024) void bn_reduce_kernel(const float* __restrict__ P,
                                                         float* __restrict__ stats) {
    int c = threadIdx.x & 255, q = threadIdx.x >> 8;
    float acc = 0.f;
#pragma unroll 8
    for (int i = q * (NB_PART / 4); i < (q + 1) * (NB_PART / 4); i++)
        acc += P[(size_t)i * 256 + c];
    __shared__ float ls[4][256];
    ls[q][c] = acc;
    __syncthreads();
    if (threadIdx.x < 256) stats[c] = ls[0][c] + ls[1][c] + ls[2][c] + ls[3][c];
}

// ---------------- launch ----------------

extern "C" void kernel_launch(void* const* d_in, const int* in_sizes, int n_in,
                              void* d_out, int out_size, void* d_ws, size_t ws_size,
                              hipStream_t stream) {
    const float* x   = (const float*)d_in[0];
    const int*   ei  = (const int*)d_in[1];
    const float* Wl0 = (const float*)d_in[2];
    const float* Wr0 = (const float*)d_in[3];
    const float* b0  = (const float*)d_in[4];
    const float* g0  = (const float*)d_in[5];
    const float* be0 = (const float*)d_in[6];
    const float* Wl1 = (const float*)d_in[7];
    const float* Wr1 = (const float*)d_in[8];
    const float* b1  = (const float*)d_in[9];
    const float* g1  = (const float*)d_in[10];
    const float* be1 = (const float*)d_in[11];
    const float* Wl2 = (const float*)d_in[12];
    const float* Wr2 = (const float*)d_in[13];
    const float* b2  = (const float*)d_in[14];

    const int N = in_sizes[0] / D_IN;   // 50000
    const int E = in_sizes[1] / 2;      // 800000

    // workspace layout (all bf16 node buffers)
    ushort_t* Hb = (ushort_t*)d_ws;                        // N*128 bf16
    ushort_t* Zb = Hb + (size_t)N * D_IN;                  // N*128 bf16 (layer2: N*64)
    ushort_t* Yb = Zb + (size_t)N * D_IN;                  // N*128 bf16
    int* cnt    = (int*)(Yb + (size_t)N * D_IN);
    int* offs   = cnt + N;
    int* cursor = offs + N + 1;
    ushort_t* sorted = (ushort_t*)(cursor + N);            // E ushort
    float* stats = (float*)(sorted + E + (E & 1));         // 512 f32 (2 layers)
    float* P = stats + 512;                                // NB_PART*256 f32
    short* WlF0 = (short*)(P + NB_PART * 256);
    short* WrF0 = WlF0 + 16384;
    short* WlF1 = WrF0 + 16384;
    short* WrF1 = WlF1 + 16384;
    short* WlF2 = WrF1 + 16384;
    short* WrF2 = WlF2 + 8192;

    const int eb = (E + 255) / 256;

    // ---- weight swizzle (also zeroes cnt) ----
    wswz_kernel<<<dim3(8, 2, 3), 256, 0, stream>>>(Wl0, Wr0, Wl1, Wr1, Wl2, Wr2,
                                                   WlF0, WrF0, WlF1, WrF1, WlF2, WrF2,
                                                   cnt, N);

    // ---- CSR build ----
    hist_kernel<<<eb, 256, 0, stream>>>(ei + E, cnt, E);
    scan_kernel<<<1, 1024, 0, stream>>>(cnt, offs, cursor, N);
    scatter_kernel<<<dim3(eb, 2), 256, 0, stream>>>(ei, ei + E, cursor, sorted, E, (N + 1) / 2);

    const int gb = (N + 63) / 64;   // 782
    const int ab = (N + 7) / 8;     // 6250

    // ---- layer 0 ----
    gemm2_mfma<128, false><<<gb, 256, 0, stream>>>(x, WlF0, WrF0, Yb, Zb,
                                                   nullptr, nullptr, nullptr, N);
    agg128_kernel<<<ab, 256, 0, stream>>>(Yb, offs, sorted, b0, Zb, Hb, N);
    bn_part_kernel<<<NB_PART, 256, 0, stream>>>(Hb, P, N);
    bn_reduce_kernel<<<1, 1024, 0, stream>>>(P, stats);

    // ---- layer 1 ----
    gemm2_mfma<128, true><<<gb, 256, 0, stream>>>(Hb, WlF1, WrF1, Yb, Zb,
                                                  stats, g0, be0, N);
    agg128_kernel<<<ab, 256, 0, stream>>>(Yb, offs, sorted, b1, Zb, Hb, N);
    bn_part_kernel<<<NB_PART, 256, 0, stream>>>(Hb, P, N);
    bn_reduce_kernel<<<1, 1024, 0, stream>>>(P, stats + 256);

    // ---- layer 2 ----
    gemm2_mfma<64, true><<<gb, 128, 0, stream>>>(Hb, WlF2, WrF2, Yb, Zb,
                                                 stats + 256, g1, be1, N);
    agg_lsm_kernel<<<ab, 256, 0, stream>>>(Yb, offs, sorted, b2, Zb, (float*)d_out, N);
}

// Round 11
// 346.372 us; speedup vs baseline: 1.1065x; 1.1065x over previous
//
#include <hip/hip_runtime.h>
#include <hip/hip_bf16.h>

#define D_IN 128
#define D_OUT 64
#define BN_EPS 1e-5f
#define NB_PART 512

typedef short short8 __attribute__((ext_vector_type(8)));
typedef float f32x4 __attribute__((ext_vector_type(4)));
typedef float f32x2 __attribute__((ext_vector_type(2)));
typedef unsigned int u32x4 __attribute__((ext_vector_type(4)));
typedef unsigned int u32x2 __attribute__((ext_vector_type(2)));
typedef unsigned short ushort_t;
typedef unsigned int uint_t;

__device__ __forceinline__ float bf16lo(uint_t v) { return __uint_as_float(v << 16); }
__device__ __forceinline__ float bf16hi(uint_t v) { return __uint_as_float(v & 0xffff0000u); }
__device__ __forceinline__ float bf2f(ushort_t u) { return __uint_as_float(((uint_t)u) << 16); }
__device__ __forceinline__ ushort_t f2bf(float f) {
    union { __hip_bfloat16 h; ushort_t u; } cv;
    cv.h = __float2bfloat16(f);
    return cv.u;
}
__device__ __forceinline__ f32x4 ntload4(const float* p) {
    return __builtin_nontemporal_load((const f32x4*)p);
}

// ---------------- CSR construction ----------------

__global__ void hist_kernel(const int* __restrict__ dst, int* __restrict__ cnt, int E) {
    int i = blockIdx.x * 256 + threadIdx.x;
    if (i < E) atomicAdd(&cnt[__builtin_nontemporal_load(&dst[i])], 1);
}

// hierarchical scan: part -> mid -> final (final also writes cursor)
__global__ void scan_part_kernel(const int* __restrict__ cnt, int* __restrict__ bsum, int n) {
    int i = blockIdx.x * 256 + threadIdx.x;
    int v = (i < n) ? cnt[i] : 0;
#pragma unroll
    for (int off = 1; off < 64; off <<= 1) v += __shfl_xor(v, off);
    __shared__ int ws[4];
    int lane = threadIdx.x & 63, wid = threadIdx.x >> 6;
    if (lane == 0) ws[wid] = v;
    __syncthreads();
    if (threadIdx.x == 0) bsum[blockIdx.x] = ws[0] + ws[1] + ws[2] + ws[3];
}

__global__ void scan_mid_kernel(const int* __restrict__ bsum, int* __restrict__ bpre,
                                int* __restrict__ offs, int PB, int n) {
    int t = threadIdx.x;
    int v = (t < PB) ? bsum[t] : 0;
    int lane = t & 63, wid = t >> 6;
    int sc = v;
#pragma unroll
    for (int off = 1; off < 64; off <<= 1) {
        int u = __shfl_up(sc, off);
        if (lane >= off) sc += u;
    }
    __shared__ int ws[4];
    if (lane == 63) ws[wid] = sc;
    __syncthreads();
    int wb = 0;
    for (int w = 0; w < 4; w++) if (w < wid) wb += ws[w];
    int incl = sc + wb;
    if (t < PB) bpre[t] = incl - v;
    if (t == PB - 1) offs[n] = incl;
}

__global__ void scan_final_kernel(const int* __restrict__ cnt, const int* __restrict__ bpre,
                                  int* __restrict__ offs, int* __restrict__ cursor, int n) {
    int b = blockIdx.x, t = threadIdx.x;
    int i = b * 256 + t;
    int v = (i < n) ? cnt[i] : 0;
    int lane = t & 63, wid = t >> 6;
    int sc = v;
#pragma unroll
    for (int off = 1; off < 64; off <<= 1) {
        int u = __shfl_up(sc, off);
        if (lane >= off) sc += u;
    }
    __shared__ int ws[4];
    if (lane == 63) ws[wid] = sc;
    __syncthreads();
    int wb = 0;
    for (int w = 0; w < 4; w++) if (w < wid) wb += ws[w];
    if (i < n) {
        int e = bpre[b] + wb + sc - v;
        offs[i] = e;
        cursor[i] = e;
    }
}

__global__ void scatter_kernel(const int* __restrict__ src, const int* __restrict__ dst,
                               int* __restrict__ cursor, ushort_t* __restrict__ sorted_src,
                               int E, int passW) {
    int lo = blockIdx.y * passW, hi = lo + passW;
    int i = blockIdx.x * 256 + threadIdx.x;
    if (i < E) {
        int d = __builtin_nontemporal_load(&dst[i]);
        if (d >= lo && d < hi) {
            int s = __builtin_nontemporal_load(&src[i]);
            int p = atomicAdd(&cursor[d], 1);
            sorted_src[p] = (ushort_t)s;
        }
    }
}

// ---------------- weight swizzle (all 3 layers) + cnt zeroing ----------------
// chunk (nf, kk): 64 lanes x 8 bf16; lane l elem j = W[kk*32 + (l>>4)*8 + j][nf*16 + (l&15)]

__global__ void wswz_kernel(const float* __restrict__ Wl0, const float* __restrict__ Wr0,
                            const float* __restrict__ Wl1, const float* __restrict__ Wr1,
                            const float* __restrict__ Wl2, const float* __restrict__ Wr2,
                            short* __restrict__ o0l, short* __restrict__ o0r,
                            short* __restrict__ o1l, short* __restrict__ o1r,
                            short* __restrict__ o2l, short* __restrict__ o2r,
                            int* __restrict__ cnt, int N) {
    // zero the histogram buffer (grid-stride over all 48 blocks)
    int fb = blockIdx.x + 8 * (blockIdx.y + 2 * blockIdx.z);
    for (int i = fb * 256 + threadIdx.x; i < N; i += 48 * 256) cnt[i] = 0;

    int layer = blockIdx.z;
    int Nn = (layer == 2) ? 64 : 128;
    const float* W;
    short* out;
    if (layer == 0) { W = blockIdx.y ? Wr0 : Wl0; out = blockIdx.y ? o0r : o0l; }
    else if (layer == 1) { W = blockIdx.y ? Wr1 : Wl1; out = blockIdx.y ? o1r : o1l; }
    else { W = blockIdx.y ? Wr2 : Wl2; out = blockIdx.y ? o2r : o2l; }
    int g = blockIdx.x * 256 + threadIdx.x;
    int nchunks = (Nn / 16) * 4;
    int chunk = g >> 6, lane = g & 63;
    if (chunk >= nchunks) return;
    int nf = chunk >> 2, kk = chunk & 3;
    short8 s;
#pragma unroll
    for (int j = 0; j < 8; j++) {
        float v = W[(size_t)(kk * 32 + (lane >> 4) * 8 + j) * Nn + nf * 16 + (lane & 15)];
        s[j] = (short)f2bf(v);
    }
    *(short8*)&out[((size_t)(chunk << 6) + lane) * 8] = s;
}

// ---------------- fused dual MFMA GEMM + on-the-fly BN/ReLU on A ----------------
// BF16IN=false: A is f32 (layer 0, no BN). BF16IN=true: A is bf16 + BN+ReLU fused.
// Both outputs bf16: Yb = a@Wl, Zb = a@Wr.

template <int TN, bool BF16IN>
__global__ __launch_bounds__(TN == 128 ? 256 : 128)
void gemm2_mfma(const void* __restrict__ Ain, const short* __restrict__ WlF,
                const short* __restrict__ WrF, ushort_t* __restrict__ Yb,
                ushort_t* __restrict__ Zb, const float* __restrict__ stats,
                const float* __restrict__ gamma, const float* __restrict__ beta, int M) {
    __shared__ short As[64 * 136];
    __shared__ float sc[128], sh[128];
    const int tid = threadIdx.x;
    const int lane = tid & 63;
    const int w = tid >> 6;
    const int row0 = blockIdx.x * 64;
    const int NT = (TN == 128) ? 256 : 128;

    if (BF16IN) {
        if (tid < 128) {
            float invM = 1.0f / (float)M;
            float mu = stats[tid] * invM;
            float var = stats[128 + tid] * invM - mu * mu;
            float scale = gamma[tid] * rsqrtf(var + BN_EPS);
            sc[tid] = scale;
            sh[tid] = beta[tid] - mu * scale;
        }
        __syncthreads();
    }

    for (int c = tid; c < 1024; c += NT) {
        int r = c >> 4, off = (c & 15) * 8;
        short8 v8 = {0, 0, 0, 0, 0, 0, 0, 0};
        if (row0 + r < M) {
            if (BF16IN) {
                const ushort_t* ap = (const ushort_t*)Ain + (size_t)(row0 + r) * 128 + off;
                short8 h = *(const short8*)ap;
#pragma unroll
                for (int j = 0; j < 8; j++) {
                    float f = bf2f((ushort_t)h[j]);
                    f = fmaxf(f * sc[off + j] + sh[off + j], 0.f);
                    v8[j] = (short)f2bf(f);
                }
            } else {
                const float* ap = (const float*)Ain + (size_t)(row0 + r) * 128 + off;
                f32x4 f0 = ntload4(ap);
                f32x4 f1 = ntload4(ap + 4);
#pragma unroll
                for (int j = 0; j < 4; j++) {
                    v8[j] = (short)f2bf(f0[j]);
                    v8[4 + j] = (short)f2bf(f1[j]);
                }
            }
        }
        *(short8*)&As[r * 136 + off] = v8;
    }
    __syncthreads();

    const short* WF;
    ushort_t* D;
    int col0;
    if (TN == 128) {
        bool isY = (w < 2);
        WF = isY ? WlF : WrF;
        D = isY ? Yb : Zb;
        col0 = (w & 1) * 64;
    } else {
        bool isY = (w == 0);
        WF = isY ? WlF : WrF;
        D = isY ? Yb : Zb;
        col0 = 0;
    }

    short8 a[4][4];
#pragma unroll
    for (int m = 0; m < 4; m++)
#pragma unroll
        for (int kk = 0; kk < 4; kk++)
            a[m][kk] = *(const short8*)&As[(m * 16 + (lane & 15)) * 136 + kk * 32 + (lane >> 4) * 8];

    f32x4 acc[4][4];
#pragma unroll
    for (int m = 0; m < 4; m++)
#pragma unroll
        for (int n = 0; n < 4; n++) acc[m][n] = (f32x4){0.f, 0.f, 0.f, 0.f};

#pragma unroll
    for (int kk = 0; kk < 4; kk++) {
#pragma unroll
        for (int n = 0; n < 4; n++) {
            short8 b = *(const short8*)&WF[(size_t)(((col0 >> 4) + n) * 4 + kk) * 512 + lane * 8];
#pragma unroll
            for (int m = 0; m < 4; m++)
                acc[m][n] = __builtin_amdgcn_mfma_f32_16x16x32_bf16(a[m][kk], b, acc[m][n], 0, 0, 0);
        }
    }

    // C/D: col = lane&15, row = (lane>>4)*4 + reg
#pragma unroll
    for (int m = 0; m < 4; m++) {
#pragma unroll
        for (int i = 0; i < 4; i++) {
            int gr = row0 + m * 16 + (lane >> 4) * 4 + i;
            if (gr < M) {
#pragma unroll
                for (int n = 0; n < 4; n++)
                    D[(size_t)gr * TN + col0 + n * 16 + (lane & 15)] = f2bf(acc[m][n][i]);
            }
        }
    }
}

// ---------------- aggregation (layers 0/1): Hb[node] = Zb[node] + mean(Yb[srcs]) + bias ----
// one wave = TWO nodes (one per 32-lane half, u32x2 = 4 cols/lane); 16 gathers in flight

__global__ __launch_bounds__(256) void agg128_kernel(const ushort_t* __restrict__ Yb,
                                                     const int* __restrict__ offs,
                                                     const ushort_t* __restrict__ sorted_src,
                                                     const float* __restrict__ bias,
                                                     const ushort_t* __restrict__ Zb,
                                                     ushort_t* __restrict__ Hb, int N) {
    int wv = blockIdx.x * 4 + (threadIdx.x >> 6);
    int lane = threadIdx.x & 63;
    int half = lane >> 5, l = lane & 31;
    int node = wv * 2 + half;
    if (node >= N) return;
    int s0 = offs[node], s1 = offs[node + 1];
    float a0 = 0.f, a1 = 0.f, a2 = 0.f, a3 = 0.f;
    int k = s0;
    for (; k + 16 <= s1; k += 16) {
        int idx[16];
#pragma unroll
        for (int j = 0; j < 16; j++) idx[j] = __builtin_nontemporal_load(&sorted_src[k + j]);
        u32x2 v[16];
#pragma unroll
        for (int j = 0; j < 16; j++) v[j] = *(const u32x2*)&Yb[(size_t)idx[j] * 128 + l * 4];
#pragma unroll
        for (int j = 0; j < 16; j++) {
            a0 += bf16lo(v[j][0]);
            a1 += bf16hi(v[j][0]);
            a2 += bf16lo(v[j][1]);
            a3 += bf16hi(v[j][1]);
        }
    }
    for (; k + 4 <= s1; k += 4) {
        int idx[4];
#pragma unroll
        for (int j = 0; j < 4; j++) idx[j] = __builtin_nontemporal_load(&sorted_src[k + j]);
#pragma unroll
        for (int j = 0; j < 4; j++) {
            u32x2 v = *(const u32x2*)&Yb[(size_t)idx[j] * 128 + l * 4];
            a0 += bf16lo(v[0]);
            a1 += bf16hi(v[0]);
            a2 += bf16lo(v[1]);
            a3 += bf16hi(v[1]);
        }
    }
    for (; k < s1; k++) {
        u32x2 v = *(const u32x2*)&Yb[(size_t)sorted_src[k] * 128 + l * 4];
        a0 += bf16lo(v[0]);
        a1 += bf16hi(v[0]);
        a2 += bf16lo(v[1]);
        a3 += bf16hi(v[1]);
    }
    float inv = 1.0f / fmaxf((float)(s1 - s0), 1.0f);
    float4 bb = *(const float4*)&bias[l * 4];
    u32x2 z = __builtin_nontemporal_load((const u32x2*)&Zb[(size_t)node * 128 + l * 4]);
    float h0 = bf16lo(z[0]) + a0 * inv + bb.x;
    float h1 = bf16hi(z[0]) + a1 * inv + bb.y;
    float h2 = bf16lo(z[1]) + a2 * inv + bb.z;
    float h3 = bf16hi(z[1]) + a3 * inv + bb.w;
    u32x2 o;
    o[0] = (uint_t)f2bf(h0) | ((uint_t)f2bf(h1) << 16);
    o[1] = (uint_t)f2bf(h2) | ((uint_t)f2bf(h3) << 16);
    __builtin_nontemporal_store(o, (u32x2*)&Hb[(size_t)node * 128 + l * 4]);
}

// ---------------- layer 2: agg + bias + log_softmax fused ----------------
// one wave = TWO nodes (one per 32-lane half); 8-deep gather unroll

__global__ __launch_bounds__(256) void agg_lsm_kernel(const ushort_t* __restrict__ Yb,
                                                      const int* __restrict__ offs,
                                                      const ushort_t* __restrict__ sorted_src,
                                                      const float* __restrict__ bias,
                                                      const ushort_t* __restrict__ Zb,
                                                      float* __restrict__ out, int N) {
    int wv = blockIdx.x * 4 + (threadIdx.x >> 6);
    int lane = threadIdx.x & 63;
    int half = lane >> 5, l = lane & 31;
    int node = wv * 2 + half;
    if (node >= N) return;
    int s0 = offs[node], s1 = offs[node + 1];
    float a0 = 0.f, a1 = 0.f;
    int k = s0;
    for (; k + 8 <= s1; k += 8) {
        int idx[8];
#pragma unroll
        for (int j = 0; j < 8; j++) idx[j] = __builtin_nontemporal_load(&sorted_src[k + j]);
        uint_t v[8];
#pragma unroll
        for (int j = 0; j < 8; j++) v[j] = *(const uint_t*)&Yb[(size_t)idx[j] * 64 + l * 2];
#pragma unroll
        for (int j = 0; j < 8; j++) {
            a0 += bf16lo(v[j]);
            a1 += bf16hi(v[j]);
        }
    }
    for (; k + 4 <= s1; k += 4) {
        int idx[4];
#pragma unroll
        for (int j = 0; j < 4; j++) idx[j] = __builtin_nontemporal_load(&sorted_src[k + j]);
#pragma unroll
        for (int j = 0; j < 4; j++) {
            uint_t v = *(const uint_t*)&Yb[(size_t)idx[j] * 64 + l * 2];
            a0 += bf16lo(v);
            a1 += bf16hi(v);
        }
    }
    for (; k < s1; k++) {
        uint_t v = *(const uint_t*)&Yb[(size_t)sorted_src[k] * 64 + l * 2];
        a0 += bf16lo(v);
        a1 += bf16hi(v);
    }
    float inv = 1.0f / fmaxf((float)(s1 - s0), 1.0f);
    uint_t z = *(const uint_t*)&Zb[(size_t)node * 64 + l * 2];
    float2 bb = *(const float2*)&bias[l * 2];
    float v0 = bf16lo(z) + a0 * inv + bb.x;
    float v1 = bf16hi(z) + a1 * inv + bb.y;
    float m = fmaxf(v0, v1);
#pragma unroll
    for (int off = 16; off; off >>= 1) m = fmaxf(m, __shfl_xor(m, off));
    float s = expf(v0 - m) + expf(v1 - m);
#pragma unroll
    for (int off = 16; off; off >>= 1) s += __shfl_xor(s, off);
    float ls = logf(s);
    f32x2 o;
    o[0] = v0 - m - ls;
    o[1] = v1 - m - ls;
    __builtin_nontemporal_store(o, (f32x2*)&out[(size_t)node * 64 + l * 2]);
}

// ---------------- BatchNorm stats: two-stage column reduction (bf16 input) ----------------

__global__ __launch_bounds__(256) void bn_part_kernel(const ushort_t* __restrict__ Hb,
                                                      float* __restrict__ P, int M) {
    int b = blockIdx.x;
    int R = (M + NB_PART - 1) / NB_PART;
    int r0 = b * R, r1 = min(r0 + R, M);
    int colg = (threadIdx.x & 15) * 8;
    int rowoff = threadIdx.x >> 4;
    float s[8], s2[8];
#pragma unroll
    for (int j = 0; j < 8; j++) { s[j] = 0.f; s2[j] = 0.f; }
    for (int r = r0 + rowoff; r < r1; r += 16) {
        u32x4 v = __builtin_nontemporal_load((const u32x4*)&Hb[(size_t)r * 128 + colg]);
#pragma unroll
        for (int q = 0; q < 4; q++) {
            float flo = bf16lo(v[q]);
            float fhi = bf16hi(v[q]);
            s[2 * q] += flo;
            s2[2 * q] += flo * flo;
            s[2 * q + 1] += fhi;
            s2[2 * q + 1] += fhi * fhi;
        }
    }
    __shared__ float ls[256][16];
#pragma unroll
    for (int j = 0; j < 8; j++) {
        ls[threadIdx.x][j] = s[j];
        ls[threadIdx.x][8 + j] = s2[j];
    }
    __syncthreads();
    if (threadIdx.x < 128) {
        int g = threadIdx.x >> 3, j = threadIdx.x & 7;
        float a = 0.f, c = 0.f;
#pragma unroll
        for (int kk = 0; kk < 16; kk++) {
            int id = kk * 16 + g;
            a += ls[id][j];
            c += ls[id][8 + j];
        }
        P[(size_t)b * 256 + threadIdx.x] = a;
        P[(size_t)b * 256 + 128 + threadIdx.x] = c;
    }
}

__global__ __launch_bounds__(1024) void bn_reduce_kernel(const float* __restrict__ P,
                                                         float* __restrict__ stats) {
    int c = threadIdx.x & 255, q = threadIdx.x >> 8;
    float acc = 0.f;
#pragma unroll 8
    for (int i = q * (NB_PART / 4); i < (q + 1) * (NB_PART / 4); i++)
        acc += P[(size_t)i * 256 + c];
    __shared__ float ls[4][256];
    ls[q][c] = acc;
    __syncthreads();
    if (threadIdx.x < 256) stats[c] = ls[0][c] + ls[1][c] + ls[2][c] + ls[3][c];
}

// ---------------- launch ----------------

extern "C" void kernel_launch(void* const* d_in, const int* in_sizes, int n_in,
                              void* d_out, int out_size, void* d_ws, size_t ws_size,
                              hipStream_t stream) {
    const float* x   = (const float*)d_in[0];
    const int*   ei  = (const int*)d_in[1];
    const float* Wl0 = (const float*)d_in[2];
    const float* Wr0 = (const float*)d_in[3];
    const float* b0  = (const float*)d_in[4];
    const float* g0  = (const float*)d_in[5];
    const float* be0 = (const float*)d_in[6];
    const float* Wl1 = (const float*)d_in[7];
    const float* Wr1 = (const float*)d_in[8];
    const float* b1  = (const float*)d_in[9];
    const float* g1  = (const float*)d_in[10];
    const float* be1 = (const float*)d_in[11];
    const float* Wl2 = (const float*)d_in[12];
    const float* Wr2 = (const float*)d_in[13];
    const float* b2  = (const float*)d_in[14];

    const int N = in_sizes[0] / D_IN;   // 50000
    const int E = in_sizes[1] / 2;      // 800000
    const int PB = (N + 255) / 256;     // 196

    // workspace layout (all bf16 node buffers)
    ushort_t* Hb = (ushort_t*)d_ws;                        // N*128 bf16
    ushort_t* Zb = Hb + (size_t)N * D_IN;                  // N*128 bf16 (layer2: N*64)
    ushort_t* Yb = Zb + (size_t)N * D_IN;                  // N*128 bf16
    int* cnt    = (int*)(Yb + (size_t)N * D_IN);
    int* offs   = cnt + N;
    int* cursor = offs + N + 1;
    int* bsum   = cursor + N;
    int* bpre   = bsum + 256;
    ushort_t* sorted = (ushort_t*)(bpre + 256);            // E ushort
    float* stats = (float*)(sorted + E + (E & 1));         // 512 f32 (2 layers)
    float* P = stats + 512;                                // NB_PART*256 f32
    short* WlF0 = (short*)(P + NB_PART * 256);
    short* WrF0 = WlF0 + 16384;
    short* WlF1 = WrF0 + 16384;
    short* WrF1 = WlF1 + 16384;
    short* WlF2 = WrF1 + 16384;
    short* WrF2 = WlF2 + 8192;

    const int eb = (E + 255) / 256;

    // ---- weight swizzle (also zeroes cnt) ----
    wswz_kernel<<<dim3(8, 2, 3), 256, 0, stream>>>(Wl0, Wr0, Wl1, Wr1, Wl2, Wr2,
                                                   WlF0, WrF0, WlF1, WrF1, WlF2, WrF2,
                                                   cnt, N);

    // ---- CSR build (hierarchical scan) ----
    hist_kernel<<<eb, 256, 0, stream>>>(ei + E, cnt, E);
    scan_part_kernel<<<PB, 256, 0, stream>>>(cnt, bsum, N);
    scan_mid_kernel<<<1, 256, 0, stream>>>(bsum, bpre, offs, PB, N);
    scan_final_kernel<<<PB, 256, 0, stream>>>(cnt, bpre, offs, cursor, N);
    scatter_kernel<<<dim3(eb, 2), 256, 0, stream>>>(ei, ei + E, cursor, sorted, E, (N + 1) / 2);

    const int gb = (N + 63) / 64;   // 782
    const int ab = (N + 7) / 8;     // 6250

    // ---- layer 0 ----
    gemm2_mfma<128, false><<<gb, 256, 0, stream>>>(x, WlF0, WrF0, Yb, Zb,
                                                   nullptr, nullptr, nullptr, N);
    agg128_kernel<<<ab, 256, 0, stream>>>(Yb, offs, sorted, b0, Zb, Hb, N);
    bn_part_kernel<<<NB_PART, 256, 0, stream>>>(Hb, P, N);
    bn_reduce_kernel<<<1, 1024, 0, stream>>>(P, stats);

    // ---- layer 1 ----
    gemm2_mfma<128, true><<<gb, 256, 0, stream>>>(Hb, WlF1, WrF1, Yb, Zb,
                                                  stats, g0, be0, N);
    agg128_kernel<<<ab, 256, 0, stream>>>(Yb, offs, sorted, b1, Zb, Hb, N);
    bn_part_kernel<<<NB_PART, 256, 0, stream>>>(Hb, P, N);
    bn_reduce_kernel<<<1, 1024, 0, stream>>>(P, stats + 256);

    // ---- layer 2 ----
    gemm2_mfma<64, true><<<gb, 128, 0, stream>>>(Hb, WlF2, WrF2, Yb, Zb,
                                                 stats + 256, g1, be1, N);
    agg_lsm_kernel<<<ab, 256, 0, stream>>>(Yb, offs, sorted, b2, Zb, (float*)d_out, N);
}